// Round 21
// baseline (68.815 us; speedup 1.0000x reference)
//
#include <hip/hip_runtime.h>
#include <hip/hip_bf16.h>

typedef __attribute__((ext_vector_type(8))) short short8;
typedef __attribute__((ext_vector_type(4))) float f32x4;

#define LOG2E 1.4426950408889634f
#define QSCALE 0.25505403955318165f   // LOG2E / sqrt(32)

static __device__ __forceinline__ unsigned short f2bf(float f){
  union { float f; unsigned u; } v; v.f = f;
  unsigned r = v.u + 0x7fffu + ((v.u >> 16) & 1u);
  return (unsigned short)(r >> 16);
}
static __device__ __forceinline__ float bf2f(unsigned short s){
  union { unsigned u; float f; } v; v.u = ((unsigned)s) << 16; return v.f;
}
// one-instruction pack of two f32 -> two bf16 (RNE); no builtin on gfx950
static __device__ __forceinline__ unsigned cvt_pk_bf16(float lo, float hi){
  unsigned r;
  asm("v_cvt_pk_bf16_f32 %0, %1, %2" : "=v"(r) : "v"(lo), "v"(hi));
  return r;
}
// async global->LDS, 16B per lane; dest must be linear (wave base + lane*16)
static __device__ __forceinline__ void gload_lds16(const void* g, void* l){
  __builtin_amdgcn_global_load_lds((const __attribute__((address_space(1))) unsigned*)g,
                                   (__attribute__((address_space(3))) unsigned*)l, 16, 0, 0);
}

// ---------------- fused prep ----------------
// blocks [0,48): w_qkv^T tiles  [48,64): w_proj^T tiles  [64,1088): bias_t  [1088,5184): LN
__global__ __launch_bounds__(256) void k_prep(
    const float* __restrict__ w_qkv, const float* __restrict__ w_proj,
    const float* __restrict__ pb, const float* __restrict__ msa,
    const float* __restrict__ ln_w, const float* __restrict__ ln_b,
    unsigned short* __restrict__ wqkvT, unsigned short* __restrict__ wprojT,
    unsigned short* __restrict__ bt, unsigned short* __restrict__ m_bf){
  __shared__ float tile[64][65];
  int b = blockIdx.x;
  int tid = threadIdx.x;
  if (b < 64){
    // 64x64 LDS tile transpose, f32 [R=256][C] -> bf16 [C][256]
    const float* in;
    unsigned short* outp;
    int C, tc;
    if (b < 48){ in = w_qkv; outp = wqkvT; C = 768; tc = 12; b -= 0; }
    else       { in = w_proj; outp = wprojT; C = 256; tc = 4;  b -= 48; }
    int r0 = (b / tc) * 64, c0 = (b % tc) * 64;
#pragma unroll
    for (int it = 0; it < 16; it++){
      int idx = tid + it*256, ri = idx >> 6, ci = idx & 63;
      tile[ri][ci] = in[(size_t)(r0+ri)*C + c0+ci];
    }
    __syncthreads();
#pragma unroll
    for (int it = 0; it < 16; it++){
      int idx = tid + it*256, co = idx >> 6, ro = idx & 63;
      outp[(size_t)(c0+co)*256 + r0+ro] = f2bf(tile[ro][co]);
    }
  } else if (b < 1088){
    // pair_bias [q][k][h] f32 -> bt [h][q][k'] bf16*LOG2E, k' = kc*64 + g*16 + tl*4 + r
    int bid = b - 64;
    int q = bid >> 1;
    int k = ((bid & 1) << 8) + tid;
    int kc = k >> 6, tl = (k >> 4) & 3, gg = (k >> 2) & 3, r = k & 3;
    int kp = kc*64 + gg*16 + tl*4 + r;
    const float* src = pb + ((size_t)q * 512 + k) * 8;
    float4 a = *(const float4*)src;
    float4 c = *(const float4*)(src + 4);
    float hv[8] = {a.x, a.y, a.z, a.w, c.x, c.y, c.z, c.w};
#pragma unroll
    for (int hh = 0; hh < 8; hh++)
      bt[((size_t)hh * 512 + q) * 512 + kp] = f2bf(hv[hh] * LOG2E);
  } else {
    int wave = tid >> 6, lane = tid & 63;
    int row = (b - 1088) * 4 + wave;
    const float* xr = msa + (size_t)row * 256 + lane * 4;
    float4 v = *(const float4*)xr;
    float s  = v.x + v.y + v.z + v.w;
    float sq = v.x*v.x + v.y*v.y + v.z*v.z + v.w*v.w;
#pragma unroll
    for (int off = 1; off < 64; off <<= 1){ s += __shfl_xor(s, off); sq += __shfl_xor(sq, off); }
    float mu = s * (1.0f/256.0f);
    float var = sq * (1.0f/256.0f) - mu*mu;
    float rs = rsqrtf(var + 1e-5f);
    float4 wv = *(const float4*)(ln_w + lane*4);
    float4 bv = *(const float4*)(ln_b + lane*4);
    uint2 o;
    o.x = cvt_pk_bf16((v.x-mu)*rs*wv.x + bv.x, (v.y-mu)*rs*wv.y + bv.y);
    o.y = cvt_pk_bf16((v.z-mu)*rs*wv.z + bv.z, (v.w-mu)*rs*wv.w + bv.w);
    *(uint2*)(m_bf + (size_t)row * 256 + lane * 4) = o;
  }
}

// ---------------- QKV GEMM: 128x128 tiles, global_load_lds staging, XCD-swizzled grid ----------------
__global__ __launch_bounds__(256) void k_gemm_qkv(const unsigned short* __restrict__ A,
    const unsigned short* __restrict__ Bt, const float* __restrict__ bias,
    unsigned short* __restrict__ Qb, unsigned short* __restrict__ Kb, unsigned short* __restrict__ Vb){
  __shared__ unsigned short As[128*64];
  __shared__ unsigned short Bs[128*64];
  int bid0 = blockIdx.x;
  int bid = (bid0 & 7) * 96 + (bid0 >> 3);   // 768 blocks: bijective XCD swizzle (768%8==0)
  int bn = bid % 6, bm = bid / 6;
  int m0 = bm * 128, e0 = bn * 128;
  int t = threadIdx.x, lane = t & 63, w = t >> 6;
  int wm = w >> 1, wn = w & 1;
  int g = lane >> 4, mm = lane & 15;
  f32x4 acc[4][4] = {};
  for (int k0 = 0; k0 < 256; k0 += 64){
    __syncthreads();
#pragma unroll
    for (int it = 0; it < 4; it++){
      int task = t + it * 256;
      int row = task >> 3, ch = task & 7;
      gload_lds16(A  + (size_t)(m0+row)*256 + k0 + ch*8, &As[task*8]);
      gload_lds16(Bt + (size_t)(e0+row)*256 + k0 + ch*8, &Bs[task*8]);
    }
    __syncthreads();
#pragma unroll
    for (int kst = 0; kst < 2; kst++){
      short8 a[4], bb[4];
#pragma unroll
      for (int i = 0; i < 4; i++)
        a[i]  = *(short8*)(&As[(wm*64 + i*16 + mm)*64 + kst*32 + g*8]);
#pragma unroll
      for (int j = 0; j < 4; j++)
        bb[j] = *(short8*)(&Bs[(wn*64 + j*16 + mm)*64 + kst*32 + g*8]);
#pragma unroll
      for (int i = 0; i < 4; i++)
#pragma unroll
        for (int j = 0; j < 4; j++)
          acc[i][j] = __builtin_amdgcn_mfma_f32_16x16x32_bf16(a[i], bb[j], acc[i][j], 0, 0, 0);
    }
  }
#pragma unroll
  for (int i = 0; i < 4; i++)
#pragma unroll
    for (int j = 0; j < 4; j++){
      int col = e0 + wn*64 + j*16 + mm;
      float bc = bias[col];
      int sidx = col >> 8, hh = (col >> 5) & 7, d = col & 31;
      unsigned short* dst = (sidx == 0) ? Qb : ((sidx == 1) ? Kb : Vb);
      float sc = (sidx == 0) ? QSCALE : 1.0f;
#pragma unroll
      for (int r = 0; r < 4; r++){
        int gm = m0 + wm*64 + i*16 + 4*g + r;
        int nn = gm >> 9, l = gm & 511;
        dst[(((size_t)nn*8 + hh)*512 + l)*32 + d] = f2bf((acc[i][j][r] + bc) * sc);
      }
    }
}

// ---------------- Attention: block per (qquad,n,h), 8 waves, no-max softmax, chunk-skewed pipeline ----------------
// K staged in LDS; V staged packed; QK MFMAs of chunk kc+1 issued BEFORE exp/PV of chunk kc
// (LDS-fed, dep-free) so the matrix pipe fills while VALU runs softmax. VGPR ~90 < 128 (free at 2 blk/CU).
__global__ __launch_bounds__(512) void k_attn(const unsigned short* __restrict__ Qb,
    const unsigned short* __restrict__ Kb, const unsigned short* __restrict__ Vb,
    const unsigned short* __restrict__ bt, unsigned short* __restrict__ Ob){
  __shared__ unsigned short Ks[512*40];
  __shared__ unsigned short Vs[32*520];
  int bid = blockIdx.x;            // ((qq*32 + n) << 3) | h   -> bid%8 == h (XCD/bias locality)
  int h = bid & 7;
  int n = (bid >> 3) & 31;
  int qq = bid >> 8;               // 0..3
  int nh = n*8 + h;
  int t = threadIdx.x;
  int lane = t & 63, wv = t >> 6;
  int g = lane >> 4, q16 = lane & 15;
  const unsigned short* kbase = Kb + (size_t)nh * 16384;
  const unsigned short* vbase = Vb + (size_t)nh * 16384;
  const unsigned short* qbase = Qb + (size_t)nh * 16384;
  {
    int row = t;  // K: 512 threads, 512 rows
    const uint4* ksrc = (const uint4*)(kbase + row * 32);
#pragma unroll
    for (int j = 0; j < 4; j++) *(uint4*)(&Ks[row*40 + j*8]) = ksrc[j];
    // V: thread handles row-pair p2=(t>>1), d-half hf=(t&1); prow permutation preserves bit0,
    // so rows 2p,2p+1 stay adjacent -> packed u32 writes
    int p2 = t >> 1, hf = t & 1;
    int r0 = p2 * 2;
    int prow0 = (r0 & ~12) | ((r0 & 4) << 1) | ((r0 & 8) >> 1);
    const uint4* v0 = (const uint4*)(vbase + (size_t)r0*32 + hf*16);
    const uint4* v1 = (const uint4*)(vbase + (size_t)(r0+1)*32 + hf*16);
    uint4 a0 = v0[0], a1 = v0[1];
    uint4 b0 = v1[0], b1 = v1[1];
    unsigned ua[8] = {a0.x,a0.y,a0.z,a0.w,a1.x,a1.y,a1.z,a1.w};
    unsigned ub[8] = {b0.x,b0.y,b0.z,b0.w,b1.x,b1.y,b1.z,b1.w};
#pragma unroll
    for (int j = 0; j < 8; j++){
      int d0 = hf*16 + 2*j;
      unsigned lo = (ua[j] & 0xffffu) | (ub[j] << 16);
      unsigned hi = (ua[j] >> 16) | (ub[j] & 0xffff0000u);
      *(unsigned*)(&Vs[d0*520 + prow0])     = lo;
      *(unsigned*)(&Vs[(d0+1)*520 + prow0]) = hi;
    }
  }
  __syncthreads();
  {
    int qb = qq*128 + wv*16;
    int qg = qb + q16;
    short8 qf = *(const short8*)(qbase + (size_t)qg * 32 + g * 8);
    const unsigned short* bq = bt + ((size_t)(h*512 + qg))*512 + g*16;
    f32x4 ls4 = {0.0f, 0.0f, 0.0f, 0.0f};
    f32x4 acc[2] = {{0,0,0,0},{0,0,0,0}};
    f32x4 zf = {0.0f, 0.0f, 0.0f, 0.0f};

    // QK for one chunk (4 MFMA fed from LDS; independent of any softmax state)
    auto qk = [&](int kc, f32x4* s){
      __builtin_amdgcn_s_setprio(1);
#pragma unroll
      for (int tl = 0; tl < 4; tl++){
        short8 kf = *(short8*)(&Ks[(kc*64 + tl*16 + q16)*40 + g*8]);
        s[tl] = __builtin_amdgcn_mfma_f32_16x16x32_bf16(kf, qf, zf, 0, 0, 0);
      }
      __builtin_amdgcn_s_setprio(0);
    };
    // exp/bias + repack + PV for one chunk
    auto process = [&](int kc, f32x4* s, uint4 w0, uint4 w1){
      union { uint4 w[2]; unsigned short u[16]; } bu;
      bu.w[0] = w0; bu.w[1] = w1;
#pragma unroll
      for (int tl = 0; tl < 4; tl++){
        f32x4 pz;
#pragma unroll
        for (int r = 0; r < 4; r++){
          float e = __builtin_amdgcn_exp2f(s[tl][r] + bf2f(bu.u[tl*4+r]));
          pz[r] = e;
          ls4[r] += e;
        }
        s[tl] = pz;
      }
#pragma unroll
      for (int cl = 0; cl < 2; cl++){
        unsigned a0 = cvt_pk_bf16(s[2*cl][0],   s[2*cl][1]);
        unsigned a1 = cvt_pk_bf16(s[2*cl][2],   s[2*cl][3]);
        unsigned b0 = cvt_pk_bf16(s[2*cl+1][0], s[2*cl+1][1]);
        unsigned b1 = cvt_pk_bf16(s[2*cl+1][2], s[2*cl+1][3]);
        asm("v_permlane32_swap_b32 %0, %1" : "+v"(a0), "+v"(b0));
        asm("v_permlane32_swap_b32 %0, %1" : "+v"(a1), "+v"(b1));
        union { unsigned w[4]; short8 pf; } u;
        u.w[0] = a0; u.w[1] = a1; u.w[2] = b0; u.w[3] = b1;
        __builtin_amdgcn_s_setprio(1);
#pragma unroll
        for (int half = 0; half < 2; half++){
          short8 vf = *(short8*)(&Vs[(half*16 + q16)*520 + kc*64 + cl*32 + g*8]);
          acc[half] = __builtin_amdgcn_mfma_f32_16x16x32_bf16(u.pf, vf, acc[half], 0, 0, 0);
        }
        __builtin_amdgcn_s_setprio(0);
      }
    };

    f32x4 sE[4], sO[4];
    // prologue: bias(0) + QK(0)
    uint4 c0 = *(const uint4*)(bq);
    uint4 c1 = *(const uint4*)(bq + 8);
    qk(0, sE);
#pragma unroll
    for (int pp = 0; pp < 4; pp++){
      int kcE = 2*pp, kcO = 2*pp + 1;
      // bias for odd chunk, then QK(odd) AHEAD of even's softmax
      uint4 n0 = *(const uint4*)(bq + kcO*64);
      uint4 n1 = *(const uint4*)(bq + kcO*64 + 8);
      qk(kcO, sO);
      process(kcE, sE, c0, c1);          // VALU overlaps QK(kcO) MFMAs
      if (pp < 3){
        c0 = *(const uint4*)(bq + (kcE+2)*64);
        c1 = *(const uint4*)(bq + (kcE+2)*64 + 8);
        qk(kcE+2, sE);                   // QK(even+2) ahead of odd's softmax
      }
      process(kcO, sO, n0, n1);
    }

    float ls = (ls4[0] + ls4[1]) + (ls4[2] + ls4[3]);
    ls += __shfl_xor(ls, 16);
    ls += __shfl_xor(ls, 32);
    float linv[4];
#pragma unroll
    for (int r = 0; r < 4; r++) linv[r] = 1.0f / __shfl(ls, 4*g + r);
#pragma unroll
    for (int half = 0; half < 2; half++)
#pragma unroll
      for (int r = 0; r < 4; r++){
        int ql = qb + 4*g + r;
        Ob[((size_t)n*512 + ql)*256 + h*32 + half*16 + q16] = f2bf(acc[half][r] * linv[r]);
      }
  }
}

// ---------------- Proj GEMM 64x128 tiles, global_load_lds staging, XCD-swizzled grid ----------------
__global__ __launch_bounds__(256) void k_gemm_proj(const unsigned short* __restrict__ A,
    const unsigned short* __restrict__ Bt, const float* __restrict__ bias,
    const float* __restrict__ msa, float* __restrict__ out){
  __shared__ unsigned short As[64*64];
  __shared__ unsigned short Bs[128*64];
  int bid0 = blockIdx.x;
  int bid = (bid0 & 7) * 64 + (bid0 >> 3);   // 512 blocks: bijective XCD swizzle (512%8==0)
  int bn = bid & 1, bm = bid >> 1;
  int m0 = bm * 64, e0 = bn * 128;
  int t = threadIdx.x, lane = t & 63, w = t >> 6;
  int g = lane >> 4, mm = lane & 15;
  f32x4 acc[4][2] = {};
  for (int k0 = 0; k0 < 256; k0 += 64){
    __syncthreads();
#pragma unroll
    for (int it = 0; it < 2; it++){
      int task = t + it * 256;
      gload_lds16(A + (size_t)(m0+(task>>3))*256 + k0 + (task&7)*8, &As[task*8]);
    }
#pragma unroll
    for (int it = 0; it < 4; it++){
      int task = t + it * 256;
      gload_lds16(Bt + (size_t)(e0+(task>>3))*256 + k0 + (task&7)*8, &Bs[task*8]);
    }
    __syncthreads();
#pragma unroll
    for (int kst = 0; kst < 2; kst++){
      short8 a[4], bb[2];
#pragma unroll
      for (int i = 0; i < 4; i++)
        a[i] = *(short8*)(&As[(i*16 + mm)*64 + kst*32 + g*8]);
#pragma unroll
      for (int j = 0; j < 2; j++)
        bb[j] = *(short8*)(&Bs[(w*32 + j*16 + mm)*64 + kst*32 + g*8]);
#pragma unroll
      for (int i = 0; i < 4; i++)
#pragma unroll
        for (int j = 0; j < 2; j++)
          acc[i][j] = __builtin_amdgcn_mfma_f32_16x16x32_bf16(a[i], bb[j], acc[i][j], 0, 0, 0);
    }
  }
#pragma unroll
  for (int i = 0; i < 4; i++)
#pragma unroll
    for (int j = 0; j < 2; j++){
      int col = e0 + w*32 + j*16 + mm;
      float bc = bias[col];
#pragma unroll
      for (int r = 0; r < 4; r++){
        int gm = m0 + i*16 + 4*g + r;
        size_t idx = (size_t)gm * 256 + col;
        out[idx] = acc[i][j][r] + bc + msa[idx];
      }
    }
}

extern "C" void kernel_launch(void* const* d_in, const int* in_sizes, int n_in,
                              void* d_out, int out_size, void* d_ws, size_t ws_size,
                              hipStream_t stream){
  const float* msa    = (const float*)d_in[0];
  const float* pb     = (const float*)d_in[1];
  const float* ln_w   = (const float*)d_in[2];
  const float* ln_b   = (const float*)d_in[3];
  const float* w_qkv  = (const float*)d_in[4];
  const float* b_qkv  = (const float*)d_in[5];
  const float* w_proj = (const float*)d_in[6];
  const float* b_proj = (const float*)d_in[7];

  unsigned short* ws     = (unsigned short*)d_ws;
  unsigned short* m_bf   = ws;                      // 16384*256
  unsigned short* wqkvT  = m_bf   + 4194304;        // 768*256
  unsigned short* wprojT = wqkvT  + 196608;         // 256*256
  unsigned short* Qb     = wprojT + 65536;          // 32*8*512*32
  unsigned short* Kb     = Qb     + 4194304;
  unsigned short* Vb     = Kb     + 4194304;
  unsigned short* Ob     = Vb     + 4194304;        // 16384*256
  unsigned short* bt     = Ob     + 4194304;        // 8*512*512 (no aliasing)
  float* out = (float*)d_out;

  k_prep<<<5184, 256, 0, stream>>>(w_qkv, w_proj, pb, msa, ln_w, ln_b, wqkvT, wprojT, bt, m_bf);
  k_gemm_qkv<<<768, 256, 0, stream>>>(m_bf, wqkvT, b_qkv, Qb, Kb, Vb);
  k_attn<<<1024, 512, 0, stream>>>(Qb, Kb, Vb, bt, Ob);
  k_gemm_proj<<<512, 256, 0, stream>>>(Ob, wprojT, b_proj, msa, out);
}

// Round 22
// 65.715 us; speedup vs baseline: 1.0472x; 1.0472x over previous
//
#include <hip/hip_runtime.h>
#include <hip/hip_bf16.h>

typedef __attribute__((ext_vector_type(8))) short short8;
typedef __attribute__((ext_vector_type(4))) float f32x4;

#define LOG2E 1.4426950408889634f
#define QSCALE 0.25505403955318165f   // LOG2E / sqrt(32)

static __device__ __forceinline__ unsigned short f2bf(float f){
  union { float f; unsigned u; } v; v.f = f;
  unsigned r = v.u + 0x7fffu + ((v.u >> 16) & 1u);
  return (unsigned short)(r >> 16);
}
static __device__ __forceinline__ float bf2f(unsigned short s){
  union { unsigned u; float f; } v; v.u = ((unsigned)s) << 16; return v.f;
}
// one-instruction pack of two f32 -> two bf16 (RNE); no builtin on gfx950
static __device__ __forceinline__ unsigned cvt_pk_bf16(float lo, float hi){
  unsigned r;
  asm("v_cvt_pk_bf16_f32 %0, %1, %2" : "=v"(r) : "v"(lo), "v"(hi));
  return r;
}
// async global->LDS, 16B per lane; dest must be linear (wave base + lane*16)
static __device__ __forceinline__ void gload_lds16(const void* g, void* l){
  __builtin_amdgcn_global_load_lds((const __attribute__((address_space(1))) unsigned*)g,
                                   (__attribute__((address_space(3))) unsigned*)l, 16, 0, 0);
}

// ---------------- fused prep ----------------
// blocks [0,48): w_qkv^T tiles  [48,64): w_proj^T tiles  [64,1088): bias_t  [1088,5184): LN
__global__ __launch_bounds__(256) void k_prep(
    const float* __restrict__ w_qkv, const float* __restrict__ w_proj,
    const float* __restrict__ pb, const float* __restrict__ msa,
    const float* __restrict__ ln_w, const float* __restrict__ ln_b,
    unsigned short* __restrict__ wqkvT, unsigned short* __restrict__ wprojT,
    unsigned short* __restrict__ bt, unsigned short* __restrict__ m_bf){
  __shared__ float tile[64][65];
  int b = blockIdx.x;
  int tid = threadIdx.x;
  if (b < 64){
    // 64x64 LDS tile transpose, f32 [R=256][C] -> bf16 [C][256]
    const float* in;
    unsigned short* outp;
    int C, tc;
    if (b < 48){ in = w_qkv; outp = wqkvT; C = 768; tc = 12; b -= 0; }
    else       { in = w_proj; outp = wprojT; C = 256; tc = 4;  b -= 48; }
    int r0 = (b / tc) * 64, c0 = (b % tc) * 64;
#pragma unroll
    for (int it = 0; it < 16; it++){
      int idx = tid + it*256, ri = idx >> 6, ci = idx & 63;
      tile[ri][ci] = in[(size_t)(r0+ri)*C + c0+ci];
    }
    __syncthreads();
#pragma unroll
    for (int it = 0; it < 16; it++){
      int idx = tid + it*256, co = idx >> 6, ro = idx & 63;
      outp[(size_t)(c0+co)*256 + r0+ro] = f2bf(tile[ro][co]);
    }
  } else if (b < 1088){
    // pair_bias [q][k][h] f32 -> bt [h][q][k'] bf16*LOG2E; permutation (swap tl<->gg fields)
    // is an INVOLUTION, so run it gather-form: linear (coalesced) writes, permuted reads.
    int bid = b - 64;
    int q = bid >> 1;
    int k = ((bid & 1) << 8) + tid;                 // OUTPUT position (linear per lane)
    int kc = k >> 6, tl = (k >> 4) & 3, gg = (k >> 2) & 3, r = k & 3;
    int ks = kc*64 + gg*16 + tl*4 + r;              // SOURCE position (perm == inverse perm)
    const float* src = pb + ((size_t)q * 512 + ks) * 8;
    float4 a = *(const float4*)src;
    float4 c = *(const float4*)(src + 4);
    float hv[8] = {a.x, a.y, a.z, a.w, c.x, c.y, c.z, c.w};
#pragma unroll
    for (int hh = 0; hh < 8; hh++)
      bt[((size_t)hh * 512 + q) * 512 + k] = f2bf(hv[hh] * LOG2E);
  } else {
    int wave = tid >> 6, lane = tid & 63;
    int row = (b - 1088) * 4 + wave;
    const float* xr = msa + (size_t)row * 256 + lane * 4;
    float4 v = *(const float4*)xr;
    float s  = v.x + v.y + v.z + v.w;
    float sq = v.x*v.x + v.y*v.y + v.z*v.z + v.w*v.w;
#pragma unroll
    for (int off = 1; off < 64; off <<= 1){ s += __shfl_xor(s, off); sq += __shfl_xor(sq, off); }
    float mu = s * (1.0f/256.0f);
    float var = sq * (1.0f/256.0f) - mu*mu;
    float rs = rsqrtf(var + 1e-5f);
    float4 wv = *(const float4*)(ln_w + lane*4);
    float4 bv = *(const float4*)(ln_b + lane*4);
    uint2 o;
    o.x = cvt_pk_bf16((v.x-mu)*rs*wv.x + bv.x, (v.y-mu)*rs*wv.y + bv.y);
    o.y = cvt_pk_bf16((v.z-mu)*rs*wv.z + bv.z, (v.w-mu)*rs*wv.w + bv.w);
    *(uint2*)(m_bf + (size_t)row * 256 + lane * 4) = o;
  }
}

// ---------------- QKV GEMM: 128x128 tiles, global_load_lds staging, XCD-swizzled grid ----------------
__global__ __launch_bounds__(256) void k_gemm_qkv(const unsigned short* __restrict__ A,
    const unsigned short* __restrict__ Bt, const float* __restrict__ bias,
    unsigned short* __restrict__ Qb, unsigned short* __restrict__ Kb, unsigned short* __restrict__ Vb){
  __shared__ unsigned short As[128*64];
  __shared__ unsigned short Bs[128*64];
  int bid0 = blockIdx.x;
  int bid = (bid0 & 7) * 96 + (bid0 >> 3);   // 768 blocks: bijective XCD swizzle (768%8==0)
  int bn = bid % 6, bm = bid / 6;
  int m0 = bm * 128, e0 = bn * 128;
  int t = threadIdx.x, lane = t & 63, w = t >> 6;
  int wm = w >> 1, wn = w & 1;
  int g = lane >> 4, mm = lane & 15;
  f32x4 acc[4][4] = {};
  for (int k0 = 0; k0 < 256; k0 += 64){
    __syncthreads();
#pragma unroll
    for (int it = 0; it < 4; it++){
      int task = t + it * 256;
      int row = task >> 3, ch = task & 7;
      gload_lds16(A  + (size_t)(m0+row)*256 + k0 + ch*8, &As[task*8]);
      gload_lds16(Bt + (size_t)(e0+row)*256 + k0 + ch*8, &Bs[task*8]);
    }
    __syncthreads();
#pragma unroll
    for (int kst = 0; kst < 2; kst++){
      short8 a[4], bb[4];
#pragma unroll
      for (int i = 0; i < 4; i++)
        a[i]  = *(short8*)(&As[(wm*64 + i*16 + mm)*64 + kst*32 + g*8]);
#pragma unroll
      for (int j = 0; j < 4; j++)
        bb[j] = *(short8*)(&Bs[(wn*64 + j*16 + mm)*64 + kst*32 + g*8]);
#pragma unroll
      for (int i = 0; i < 4; i++)
#pragma unroll
        for (int j = 0; j < 4; j++)
          acc[i][j] = __builtin_amdgcn_mfma_f32_16x16x32_bf16(a[i], bb[j], acc[i][j], 0, 0, 0);
    }
  }
#pragma unroll
  for (int i = 0; i < 4; i++)
#pragma unroll
    for (int j = 0; j < 4; j++){
      int col = e0 + wn*64 + j*16 + mm;
      float bc = bias[col];
      int sidx = col >> 8, hh = (col >> 5) & 7, d = col & 31;
      unsigned short* dst = (sidx == 0) ? Qb : ((sidx == 1) ? Kb : Vb);
      float sc = (sidx == 0) ? QSCALE : 1.0f;
#pragma unroll
      for (int r = 0; r < 4; r++){
        int gm = m0 + wm*64 + i*16 + 4*g + r;
        int nn = gm >> 9, l = gm & 511;
        dst[(((size_t)nn*8 + hh)*512 + l)*32 + d] = f2bf((acc[i][j][r] + bc) * sc);
      }
    }
}

// ---------------- Attention: block per (qhalf,n,h), 8 waves, TWO independent q-groups per wave ----------------
// K staged in LDS once per block; V staged as packed row-pairs (u32 LDS writes);
// kf/vf LDS reads shared by both q-groups (A: rows qb.., B: +128).
__global__ __launch_bounds__(512) void k_attn(const unsigned short* __restrict__ Qb,
    const unsigned short* __restrict__ Kb, const unsigned short* __restrict__ Vb,
    const unsigned short* __restrict__ bt, unsigned short* __restrict__ Ob){
  __shared__ unsigned short Ks[512*40];
  __shared__ unsigned short Vs[32*520];
  int bid = blockIdx.x;            // ((qh*32 + n) << 3) | h   -> bid%8 == h (XCD/bias locality)
  int h = bid & 7;
  int n = (bid >> 3) & 31;
  int qh = bid >> 8;               // 0..1
  int nh = n*8 + h;
  int t = threadIdx.x;
  int lane = t & 63, wv = t >> 6;
  int g = lane >> 4, q16 = lane & 15;
  const unsigned short* kbase = Kb + (size_t)nh * 16384;
  const unsigned short* vbase = Vb + (size_t)nh * 16384;
  const unsigned short* qbase = Qb + (size_t)nh * 16384;
  {
    int row = t;  // K: 512 threads, 512 rows
    const uint4* ksrc = (const uint4*)(kbase + row * 32);
#pragma unroll
    for (int j = 0; j < 4; j++) *(uint4*)(&Ks[row*40 + j*8]) = ksrc[j];
    // V: thread handles row-pair p2=(t>>1), d-half hf=(t&1); prow permutation preserves bit0,
    // so rows 2p,2p+1 stay adjacent -> packed u32 writes (V[2p][d] | V[2p+1][d]<<16)
    int p2 = t >> 1, hf = t & 1;
    int r0 = p2 * 2;
    int prow0 = (r0 & ~12) | ((r0 & 4) << 1) | ((r0 & 8) >> 1);
    const uint4* v0 = (const uint4*)(vbase + (size_t)r0*32 + hf*16);
    const uint4* v1 = (const uint4*)(vbase + (size_t)(r0+1)*32 + hf*16);
    uint4 a0 = v0[0], a1 = v0[1];
    uint4 b0 = v1[0], b1 = v1[1];
    unsigned ua[8] = {a0.x,a0.y,a0.z,a0.w,a1.x,a1.y,a1.z,a1.w};
    unsigned ub[8] = {b0.x,b0.y,b0.z,b0.w,b1.x,b1.y,b1.z,b1.w};
#pragma unroll
    for (int j = 0; j < 8; j++){
      int d0 = hf*16 + 2*j;
      unsigned lo = (ua[j] & 0xffffu) | (ub[j] << 16);
      unsigned hi = (ua[j] >> 16) | (ub[j] & 0xffff0000u);
      *(unsigned*)(&Vs[d0*520 + prow0])     = lo;
      *(unsigned*)(&Vs[(d0+1)*520 + prow0]) = hi;
    }
  }
  __syncthreads();
  {
    int qb = qh*256 + wv*16;       // group A rows; group B = qb + 128
    int qgA = qb + q16, qgB = qgA + 128;
    short8 qfA = *(const short8*)(qbase + (size_t)qgA * 32 + g * 8);
    short8 qfB = *(const short8*)(qbase + (size_t)qgB * 32 + g * 8);
    const unsigned short* bqA = bt + ((size_t)(h*512 + qgA))*512 + g*16;
    const unsigned short* bqB = bt + ((size_t)(h*512 + qgB))*512 + g*16;
    f32x4 lsA = {0.0f, 0.0f, 0.0f, 0.0f}, lsB = {0.0f, 0.0f, 0.0f, 0.0f};
    f32x4 accA[2] = {{0,0,0,0},{0,0,0,0}};
    f32x4 accB[2] = {{0,0,0,0},{0,0,0,0}};
    f32x4 zf = {0.0f, 0.0f, 0.0f, 0.0f};
    // bias prefetch, one chunk ahead (named registers)
    uint4 bnA0 = *(const uint4*)(bqA), bnA1 = *(const uint4*)(bqA + 8);
    uint4 bnB0 = *(const uint4*)(bqB), bnB1 = *(const uint4*)(bqB + 8);
#pragma unroll 2
    for (int kc = 0; kc < 8; kc++){
      union { uint4 w[2]; unsigned short u[16]; } buA, buB;
      buA.w[0] = bnA0; buA.w[1] = bnA1;
      buB.w[0] = bnB0; buB.w[1] = bnB1;
      if (kc < 7){
        bnA0 = *(const uint4*)(bqA + (kc+1)*64);
        bnA1 = *(const uint4*)(bqA + (kc+1)*64 + 8);
        bnB0 = *(const uint4*)(bqB + (kc+1)*64);
        bnB1 = *(const uint4*)(bqB + (kc+1)*64 + 8);
      }
      // QK^T (swapped): kf shared by both q-groups
      f32x4 sA[4], sB[4];
      __builtin_amdgcn_s_setprio(1);
#pragma unroll
      for (int tl = 0; tl < 4; tl++){
        short8 kf = *(short8*)(&Ks[(kc*64 + tl*16 + q16)*40 + g*8]);
        sA[tl] = __builtin_amdgcn_mfma_f32_16x16x32_bf16(kf, qfA, zf, 0, 0, 0);
        sB[tl] = __builtin_amdgcn_mfma_f32_16x16x32_bf16(kf, qfB, zf, 0, 0, 0);
      }
      __builtin_amdgcn_s_setprio(0);
      // +bias (prefetched), exp2 (raw), partial row-sums
#pragma unroll
      for (int tl = 0; tl < 4; tl++){
#pragma unroll
        for (int r = 0; r < 4; r++){
          float eA = __builtin_amdgcn_exp2f(sA[tl][r] + bf2f(buA.u[tl*4+r]));
          sA[tl][r] = eA; lsA[r] += eA;
          float eB = __builtin_amdgcn_exp2f(sB[tl][r] + bf2f(buB.u[tl*4+r]));
          sB[tl][r] = eB; lsB[r] += eB;
        }
      }
      // PV: repack both groups via cvt_pk + permlane32_swap; vf shared
#pragma unroll
      for (int cl = 0; cl < 2; cl++){
        unsigned a0A = cvt_pk_bf16(sA[2*cl][0],   sA[2*cl][1]);
        unsigned a1A = cvt_pk_bf16(sA[2*cl][2],   sA[2*cl][3]);
        unsigned b0A = cvt_pk_bf16(sA[2*cl+1][0], sA[2*cl+1][1]);
        unsigned b1A = cvt_pk_bf16(sA[2*cl+1][2], sA[2*cl+1][3]);
        asm("v_permlane32_swap_b32 %0, %1" : "+v"(a0A), "+v"(b0A));
        asm("v_permlane32_swap_b32 %0, %1" : "+v"(a1A), "+v"(b1A));
        unsigned a0B = cvt_pk_bf16(sB[2*cl][0],   sB[2*cl][1]);
        unsigned a1B = cvt_pk_bf16(sB[2*cl][2],   sB[2*cl][3]);
        unsigned b0B = cvt_pk_bf16(sB[2*cl+1][0], sB[2*cl+1][1]);
        unsigned b1B = cvt_pk_bf16(sB[2*cl+1][2], sB[2*cl+1][3]);
        asm("v_permlane32_swap_b32 %0, %1" : "+v"(a0B), "+v"(b0B));
        asm("v_permlane32_swap_b32 %0, %1" : "+v"(a1B), "+v"(b1B));
        union { unsigned w[4]; short8 pf; } uA, uB;
        uA.w[0] = a0A; uA.w[1] = a1A; uA.w[2] = b0A; uA.w[3] = b1A;
        uB.w[0] = a0B; uB.w[1] = a1B; uB.w[2] = b0B; uB.w[3] = b1B;
        __builtin_amdgcn_s_setprio(1);
#pragma unroll
        for (int half = 0; half < 2; half++){
          short8 vf = *(short8*)(&Vs[(half*16 + q16)*520 + kc*64 + cl*32 + g*8]);
          accA[half] = __builtin_amdgcn_mfma_f32_16x16x32_bf16(uA.pf, vf, accA[half], 0, 0, 0);
          accB[half] = __builtin_amdgcn_mfma_f32_16x16x32_bf16(uB.pf, vf, accB[half], 0, 0, 0);
        }
        __builtin_amdgcn_s_setprio(0);
      }
    }
    float lA = (lsA[0] + lsA[1]) + (lsA[2] + lsA[3]);
    lA += __shfl_xor(lA, 16);
    lA += __shfl_xor(lA, 32);
    float lB = (lsB[0] + lsB[1]) + (lsB[2] + lsB[3]);
    lB += __shfl_xor(lB, 16);
    lB += __shfl_xor(lB, 32);
    float linvA[4], linvB[4];
#pragma unroll
    for (int r = 0; r < 4; r++){
      linvA[r] = 1.0f / __shfl(lA, 4*g + r);
      linvB[r] = 1.0f / __shfl(lB, 4*g + r);
    }
#pragma unroll
    for (int half = 0; half < 2; half++)
#pragma unroll
      for (int r = 0; r < 4; r++){
        int ql = qb + 4*g + r;
        Ob[((size_t)n*512 + ql)*256 + h*32 + half*16 + q16] = f2bf(accA[half][r] * linvA[r]);
        Ob[((size_t)n*512 + ql + 128)*256 + h*32 + half*16 + q16] = f2bf(accB[half][r] * linvB[r]);
      }
  }
}

// ---------------- Proj GEMM 64x128 tiles, global_load_lds staging, XCD-swizzled grid ----------------
__global__ __launch_bounds__(256) void k_gemm_proj(const unsigned short* __restrict__ A,
    const unsigned short* __restrict__ Bt, const float* __restrict__ bias,
    const float* __restrict__ msa, float* __restrict__ out){
  __shared__ unsigned short As[64*64];
  __shared__ unsigned short Bs[128*64];
  int bid0 = blockIdx.x;
  int bid = (bid0 & 7) * 64 + (bid0 >> 3);   // 512 blocks: bijective XCD swizzle (512%8==0)
  int bn = bid & 1, bm = bid >> 1;
  int m0 = bm * 64, e0 = bn * 128;
  int t = threadIdx.x, lane = t & 63, w = t >> 6;
  int g = lane >> 4, mm = lane & 15;
  f32x4 acc[4][2] = {};
  for (int k0 = 0; k0 < 256; k0 += 64){
    __syncthreads();
#pragma unroll
    for (int it = 0; it < 2; it++){
      int task = t + it * 256;
      gload_lds16(A + (size_t)(m0+(task>>3))*256 + k0 + (task&7)*8, &As[task*8]);
    }
#pragma unroll
    for (int it = 0; it < 4; it++){
      int task = t + it * 256;
      gload_lds16(Bt + (size_t)(e0+(task>>3))*256 + k0 + (task&7)*8, &Bs[task*8]);
    }
    __syncthreads();
#pragma unroll
    for (int kst = 0; kst < 2; kst++){
      short8 a[4], bb[2];
#pragma unroll
      for (int i = 0; i < 4; i++)
        a[i] = *(short8*)(&As[(i*16 + mm)*64 + kst*32 + g*8]);
#pragma unroll
      for (int j = 0; j < 2; j++)
        bb[j] = *(short8*)(&Bs[(w*32 + j*16 + mm)*64 + kst*32 + g*8]);
#pragma unroll
      for (int i = 0; i < 4; i++)
#pragma unroll
        for (int j = 0; j < 2; j++)
          acc[i][j] = __builtin_amdgcn_mfma_f32_16x16x32_bf16(a[i], bb[j], acc[i][j], 0, 0, 0);
    }
  }
#pragma unroll
  for (int i = 0; i < 4; i++)
#pragma unroll
    for (int j = 0; j < 2; j++){
      int col = e0 + w*32 + j*16 + mm;
      float bc = bias[col];
#pragma unroll
      for (int r = 0; r < 4; r++){
        int gm = m0 + i*16 + 4*g + r;
        size_t idx = (size_t)gm * 256 + col;
        out[idx] = acc[i][j][r] + bc + msa[idx];
      }
    }
}

extern "C" void kernel_launch(void* const* d_in, const int* in_sizes, int n_in,
                              void* d_out, int out_size, void* d_ws, size_t ws_size,
                              hipStream_t stream){
  const float* msa    = (const float*)d_in[0];
  const float* pb     = (const float*)d_in[1];
  const float* ln_w   = (const float*)d_in[2];
  const float* ln_b   = (const float*)d_in[3];
  const float* w_qkv  = (const float*)d_in[4];
  const float* b_qkv  = (const float*)d_in[5];
  const float* w_proj = (const float*)d_in[6];
  const float* b_proj = (const float*)d_in[7];

  unsigned short* ws     = (unsigned short*)d_ws;
  unsigned short* m_bf   = ws;                      // 16384*256
  unsigned short* wqkvT  = m_bf   + 4194304;        // 768*256
  unsigned short* wprojT = wqkvT  + 196608;         // 256*256
  unsigned short* Qb     = wprojT + 65536;          // 32*8*512*32
  unsigned short* Kb     = Qb     + 4194304;
  unsigned short* Vb     = Kb     + 4194304;
  unsigned short* Ob     = Vb     + 4194304;        // 16384*256
  unsigned short* bt     = Ob     + 4194304;        // 8*512*512 (no aliasing)
  float* out = (float*)d_out;

  k_prep<<<5184, 256, 0, stream>>>(w_qkv, w_proj, pb, msa, ln_w, ln_b, wqkvT, wprojT, bt, m_bf);
  k_gemm_qkv<<<768, 256, 0, stream>>>(m_bf, wqkvT, b_qkv, Qb, Kb, Vb);
  k_attn<<<512, 512, 0, stream>>>(Qb, Kb, Vb, bt, Ob);
  k_gemm_proj<<<512, 256, 0, stream>>>(Ob, wprojT, b_proj, msa, out);
}

// Round 23
// 65.153 us; speedup vs baseline: 1.0562x; 1.0086x over previous
//
#include <hip/hip_runtime.h>
#include <hip/hip_bf16.h>

typedef __attribute__((ext_vector_type(8))) short short8;
typedef __attribute__((ext_vector_type(4))) float f32x4;

#define LOG2E 1.4426950408889634f
#define QSCALE 0.25505403955318165f   // LOG2E / sqrt(32)

static __device__ __forceinline__ unsigned short f2bf(float f){
  union { float f; unsigned u; } v; v.f = f;
  unsigned r = v.u + 0x7fffu + ((v.u >> 16) & 1u);
  return (unsigned short)(r >> 16);
}
static __device__ __forceinline__ float bf2f(unsigned short s){
  union { unsigned u; float f; } v; v.u = ((unsigned)s) << 16; return v.f;
}
// one-instruction pack of two f32 -> two bf16 (RNE); no builtin on gfx950
static __device__ __forceinline__ unsigned cvt_pk_bf16(float lo, float hi){
  unsigned r;
  asm("v_cvt_pk_bf16_f32 %0, %1, %2" : "=v"(r) : "v"(lo), "v"(hi));
  return r;
}
// async global->LDS, 16B per lane; dest must be linear (wave base + lane*16)
static __device__ __forceinline__ void gload_lds16(const void* g, void* l){
  __builtin_amdgcn_global_load_lds((const __attribute__((address_space(1))) unsigned*)g,
                                   (__attribute__((address_space(3))) unsigned*)l, 16, 0, 0);
}

// ---------------- fused prep ----------------
// blocks [0,48): w_qkv^T tiles  [48,64): w_proj^T tiles  [64,1088): bias_t  [1088,5184): LN
__global__ __launch_bounds__(256) void k_prep(
    const float* __restrict__ w_qkv, const float* __restrict__ w_proj,
    const float* __restrict__ pb, const float* __restrict__ msa,
    const float* __restrict__ ln_w, const float* __restrict__ ln_b,
    unsigned short* __restrict__ wqkvT, unsigned short* __restrict__ wprojT,
    unsigned short* __restrict__ bt, unsigned short* __restrict__ m_bf){
  __shared__ float tile[64][65];
  int b = blockIdx.x;
  int tid = threadIdx.x;
  if (b < 64){
    // 64x64 LDS tile transpose, f32 [R=256][C] -> bf16 [C][256]
    const float* in;
    unsigned short* outp;
    int C, tc;
    if (b < 48){ in = w_qkv; outp = wqkvT; C = 768; tc = 12; b -= 0; }
    else       { in = w_proj; outp = wprojT; C = 256; tc = 4;  b -= 48; }
    int r0 = (b / tc) * 64, c0 = (b % tc) * 64;
#pragma unroll
    for (int it = 0; it < 16; it++){
      int idx = tid + it*256, ri = idx >> 6, ci = idx & 63;
      tile[ri][ci] = in[(size_t)(r0+ri)*C + c0+ci];
    }
    __syncthreads();
#pragma unroll
    for (int it = 0; it < 16; it++){
      int idx = tid + it*256, co = idx >> 6, ro = idx & 63;
      outp[(size_t)(c0+co)*256 + r0+ro] = f2bf(tile[ro][co]);
    }
  } else if (b < 1088){
    // pair_bias [q][k][h] f32 -> bt [h][q][k'] bf16*LOG2E; permutation (swap tl<->gg fields)
    // is an INVOLUTION, so run it gather-form: linear (coalesced) writes, permuted reads.
    int bid = b - 64;
    int q = bid >> 1;
    int k = ((bid & 1) << 8) + tid;                 // OUTPUT position (linear per lane)
    int kc = k >> 6, tl = (k >> 4) & 3, gg = (k >> 2) & 3, r = k & 3;
    int ks = kc*64 + gg*16 + tl*4 + r;              // SOURCE position (perm == inverse perm)
    const float* src = pb + ((size_t)q * 512 + ks) * 8;
    float4 a = *(const float4*)src;
    float4 c = *(const float4*)(src + 4);
    float hv[8] = {a.x, a.y, a.z, a.w, c.x, c.y, c.z, c.w};
#pragma unroll
    for (int hh = 0; hh < 8; hh++)
      bt[((size_t)hh * 512 + q) * 512 + k] = f2bf(hv[hh] * LOG2E);
  } else {
    int wave = tid >> 6, lane = tid & 63;
    int row = (b - 1088) * 4 + wave;
    const float* xr = msa + (size_t)row * 256 + lane * 4;
    float4 v = *(const float4*)xr;
    float s  = v.x + v.y + v.z + v.w;
    float sq = v.x*v.x + v.y*v.y + v.z*v.z + v.w*v.w;
#pragma unroll
    for (int off = 1; off < 64; off <<= 1){ s += __shfl_xor(s, off); sq += __shfl_xor(sq, off); }
    float mu = s * (1.0f/256.0f);
    float var = sq * (1.0f/256.0f) - mu*mu;
    float rs = rsqrtf(var + 1e-5f);
    float4 wv = *(const float4*)(ln_w + lane*4);
    float4 bv = *(const float4*)(ln_b + lane*4);
    uint2 o;
    o.x = cvt_pk_bf16((v.x-mu)*rs*wv.x + bv.x, (v.y-mu)*rs*wv.y + bv.y);
    o.y = cvt_pk_bf16((v.z-mu)*rs*wv.z + bv.z, (v.w-mu)*rs*wv.w + bv.w);
    *(uint2*)(m_bf + (size_t)row * 256 + lane * 4) = o;
  }
}

// ---------------- QKV GEMM: 128x128 tiles, global_load_lds staging, XCD-swizzled grid ----------------
__global__ __launch_bounds__(256) void k_gemm_qkv(const unsigned short* __restrict__ A,
    const unsigned short* __restrict__ Bt, const float* __restrict__ bias,
    unsigned short* __restrict__ Qb, unsigned short* __restrict__ Kb, unsigned short* __restrict__ Vb){
  __shared__ unsigned short As[128*64];
  __shared__ unsigned short Bs[128*64];
  int bid0 = blockIdx.x;
  int bid = (bid0 & 7) * 96 + (bid0 >> 3);   // 768 blocks: bijective XCD swizzle (768%8==0)
  int bn = bid % 6, bm = bid / 6;
  int m0 = bm * 128, e0 = bn * 128;
  int t = threadIdx.x, lane = t & 63, w = t >> 6;
  int wm = w >> 1, wn = w & 1;
  int g = lane >> 4, mm = lane & 15;
  f32x4 acc[4][4] = {};
  for (int k0 = 0; k0 < 256; k0 += 64){
    __syncthreads();
#pragma unroll
    for (int it = 0; it < 4; it++){
      int task = t + it * 256;
      int row = task >> 3, ch = task & 7;
      gload_lds16(A  + (size_t)(m0+row)*256 + k0 + ch*8, &As[task*8]);
      gload_lds16(Bt + (size_t)(e0+row)*256 + k0 + ch*8, &Bs[task*8]);
    }
    __syncthreads();
#pragma unroll
    for (int kst = 0; kst < 2; kst++){
      short8 a[4], bb[4];
#pragma unroll
      for (int i = 0; i < 4; i++)
        a[i]  = *(short8*)(&As[(wm*64 + i*16 + mm)*64 + kst*32 + g*8]);
#pragma unroll
      for (int j = 0; j < 4; j++)
        bb[j] = *(short8*)(&Bs[(wn*64 + j*16 + mm)*64 + kst*32 + g*8]);
#pragma unroll
      for (int i = 0; i < 4; i++)
#pragma unroll
        for (int j = 0; j < 4; j++)
          acc[i][j] = __builtin_amdgcn_mfma_f32_16x16x32_bf16(a[i], bb[j], acc[i][j], 0, 0, 0);
    }
  }
#pragma unroll
  for (int i = 0; i < 4; i++)
#pragma unroll
    for (int j = 0; j < 4; j++){
      int col = e0 + wn*64 + j*16 + mm;
      float bc = bias[col];
      int sidx = col >> 8, hh = (col >> 5) & 7, d = col & 31;
      unsigned short* dst = (sidx == 0) ? Qb : ((sidx == 1) ? Kb : Vb);
      float sc = (sidx == 0) ? QSCALE : 1.0f;
#pragma unroll
      for (int r = 0; r < 4; r++){
        int gm = m0 + wm*64 + i*16 + 4*g + r;
        int nn = gm >> 9, l = gm & 511;
        dst[(((size_t)nn*8 + hh)*512 + l)*32 + d] = f2bf((acc[i][j][r] + bc) * sc);
      }
    }
}

// ---------------- Attention: block per (n,h), 8 waves; K/V staged ONCE, two qh passes ----------------
// Staging amortized over all 512 q-rows (was 2 blocks staging identical K/V).
// Per-pass body = r20-proven dual q-group (A: rows qb.., B: +128); kf/vf LDS reads shared.
__global__ __launch_bounds__(512) void k_attn(const unsigned short* __restrict__ Qb,
    const unsigned short* __restrict__ Kb, const unsigned short* __restrict__ Vb,
    const unsigned short* __restrict__ bt, unsigned short* __restrict__ Ob){
  __shared__ unsigned short Ks[512*40];
  __shared__ unsigned short Vs[32*520];
  int bid = blockIdx.x;            // (n << 3) | h   -> bid%8 == h (XCD/bias locality)
  int h = bid & 7;
  int n = bid >> 3;                // 0..31
  int nh = n*8 + h;
  int t = threadIdx.x;
  int lane = t & 63, wv = t >> 6;
  int g = lane >> 4, q16 = lane & 15;
  const unsigned short* kbase = Kb + (size_t)nh * 16384;
  const unsigned short* vbase = Vb + (size_t)nh * 16384;
  const unsigned short* qbase = Qb + (size_t)nh * 16384;
  {
    int row = t;  // K: 512 threads, 512 rows
    const uint4* ksrc = (const uint4*)(kbase + row * 32);
#pragma unroll
    for (int j = 0; j < 4; j++) *(uint4*)(&Ks[row*40 + j*8]) = ksrc[j];
    // V: thread handles row-pair p2=(t>>1), d-half hf=(t&1); prow permutation preserves bit0,
    // so rows 2p,2p+1 stay adjacent -> packed u32 writes (V[2p][d] | V[2p+1][d]<<16)
    int p2 = t >> 1, hf = t & 1;
    int r0 = p2 * 2;
    int prow0 = (r0 & ~12) | ((r0 & 4) << 1) | ((r0 & 8) >> 1);
    const uint4* v0 = (const uint4*)(vbase + (size_t)r0*32 + hf*16);
    const uint4* v1 = (const uint4*)(vbase + (size_t)(r0+1)*32 + hf*16);
    uint4 a0 = v0[0], a1 = v0[1];
    uint4 b0 = v1[0], b1 = v1[1];
    unsigned ua[8] = {a0.x,a0.y,a0.z,a0.w,a1.x,a1.y,a1.z,a1.w};
    unsigned ub[8] = {b0.x,b0.y,b0.z,b0.w,b1.x,b1.y,b1.z,b1.w};
#pragma unroll
    for (int j = 0; j < 8; j++){
      int d0 = hf*16 + 2*j;
      unsigned lo = (ua[j] & 0xffffu) | (ub[j] << 16);
      unsigned hi = (ua[j] >> 16) | (ub[j] & 0xffff0000u);
      *(unsigned*)(&Vs[d0*520 + prow0])     = lo;
      *(unsigned*)(&Vs[(d0+1)*520 + prow0]) = hi;
    }
  }
  __syncthreads();
  for (int qh = 0; qh < 2; qh++){
    int qb = qh*256 + wv*16;       // group A rows; group B = qb + 128
    int qgA = qb + q16, qgB = qgA + 128;
    short8 qfA = *(const short8*)(qbase + (size_t)qgA * 32 + g * 8);
    short8 qfB = *(const short8*)(qbase + (size_t)qgB * 32 + g * 8);
    const unsigned short* bqA = bt + ((size_t)(h*512 + qgA))*512 + g*16;
    const unsigned short* bqB = bt + ((size_t)(h*512 + qgB))*512 + g*16;
    f32x4 lsA = {0.0f, 0.0f, 0.0f, 0.0f}, lsB = {0.0f, 0.0f, 0.0f, 0.0f};
    f32x4 accA[2] = {{0,0,0,0},{0,0,0,0}};
    f32x4 accB[2] = {{0,0,0,0},{0,0,0,0}};
    f32x4 zf = {0.0f, 0.0f, 0.0f, 0.0f};
    // bias prefetch, one chunk ahead (named registers)
    uint4 bnA0 = *(const uint4*)(bqA), bnA1 = *(const uint4*)(bqA + 8);
    uint4 bnB0 = *(const uint4*)(bqB), bnB1 = *(const uint4*)(bqB + 8);
#pragma unroll 2
    for (int kc = 0; kc < 8; kc++){
      union { uint4 w[2]; unsigned short u[16]; } buA, buB;
      buA.w[0] = bnA0; buA.w[1] = bnA1;
      buB.w[0] = bnB0; buB.w[1] = bnB1;
      if (kc < 7){
        bnA0 = *(const uint4*)(bqA + (kc+1)*64);
        bnA1 = *(const uint4*)(bqA + (kc+1)*64 + 8);
        bnB0 = *(const uint4*)(bqB + (kc+1)*64);
        bnB1 = *(const uint4*)(bqB + (kc+1)*64 + 8);
      }
      // QK^T (swapped): kf shared by both q-groups
      f32x4 sA[4], sB[4];
      __builtin_amdgcn_s_setprio(1);
#pragma unroll
      for (int tl = 0; tl < 4; tl++){
        short8 kf = *(short8*)(&Ks[(kc*64 + tl*16 + q16)*40 + g*8]);
        sA[tl] = __builtin_amdgcn_mfma_f32_16x16x32_bf16(kf, qfA, zf, 0, 0, 0);
        sB[tl] = __builtin_amdgcn_mfma_f32_16x16x32_bf16(kf, qfB, zf, 0, 0, 0);
      }
      __builtin_amdgcn_s_setprio(0);
      // +bias (prefetched), exp2 (raw), partial row-sums
#pragma unroll
      for (int tl = 0; tl < 4; tl++){
#pragma unroll
        for (int r = 0; r < 4; r++){
          float eA = __builtin_amdgcn_exp2f(sA[tl][r] + bf2f(buA.u[tl*4+r]));
          sA[tl][r] = eA; lsA[r] += eA;
          float eB = __builtin_amdgcn_exp2f(sB[tl][r] + bf2f(buB.u[tl*4+r]));
          sB[tl][r] = eB; lsB[r] += eB;
        }
      }
      // PV: repack both groups via cvt_pk + permlane32_swap; vf shared
#pragma unroll
      for (int cl = 0; cl < 2; cl++){
        unsigned a0A = cvt_pk_bf16(sA[2*cl][0],   sA[2*cl][1]);
        unsigned a1A = cvt_pk_bf16(sA[2*cl][2],   sA[2*cl][3]);
        unsigned b0A = cvt_pk_bf16(sA[2*cl+1][0], sA[2*cl+1][1]);
        unsigned b1A = cvt_pk_bf16(sA[2*cl+1][2], sA[2*cl+1][3]);
        asm("v_permlane32_swap_b32 %0, %1" : "+v"(a0A), "+v"(b0A));
        asm("v_permlane32_swap_b32 %0, %1" : "+v"(a1A), "+v"(b1A));
        unsigned a0B = cvt_pk_bf16(sB[2*cl][0],   sB[2*cl][1]);
        unsigned a1B = cvt_pk_bf16(sB[2*cl][2],   sB[2*cl][3]);
        unsigned b0B = cvt_pk_bf16(sB[2*cl+1][0], sB[2*cl+1][1]);
        unsigned b1B = cvt_pk_bf16(sB[2*cl+1][2], sB[2*cl+1][3]);
        asm("v_permlane32_swap_b32 %0, %1" : "+v"(a0B), "+v"(b0B));
        asm("v_permlane32_swap_b32 %0, %1" : "+v"(a1B), "+v"(b1B));
        union { unsigned w[4]; short8 pf; } uA, uB;
        uA.w[0] = a0A; uA.w[1] = a1A; uA.w[2] = b0A; uA.w[3] = b1A;
        uB.w[0] = a0B; uB.w[1] = a1B; uB.w[2] = b0B; uB.w[3] = b1B;
        __builtin_amdgcn_s_setprio(1);
#pragma unroll
        for (int half = 0; half < 2; half++){
          short8 vf = *(short8*)(&Vs[(half*16 + q16)*520 + kc*64 + cl*32 + g*8]);
          accA[half] = __builtin_amdgcn_mfma_f32_16x16x32_bf16(uA.pf, vf, accA[half], 0, 0, 0);
          accB[half] = __builtin_amdgcn_mfma_f32_16x16x32_bf16(uB.pf, vf, accB[half], 0, 0, 0);
        }
        __builtin_amdgcn_s_setprio(0);
      }
    }
    float lA = (lsA[0] + lsA[1]) + (lsA[2] + lsA[3]);
    lA += __shfl_xor(lA, 16);
    lA += __shfl_xor(lA, 32);
    float lB = (lsB[0] + lsB[1]) + (lsB[2] + lsB[3]);
    lB += __shfl_xor(lB, 16);
    lB += __shfl_xor(lB, 32);
    float linvA[4], linvB[4];
#pragma unroll
    for (int r = 0; r < 4; r++){
      linvA[r] = 1.0f / __shfl(lA, 4*g + r);
      linvB[r] = 1.0f / __shfl(lB, 4*g + r);
    }
#pragma unroll
    for (int half = 0; half < 2; half++)
#pragma unroll
      for (int r = 0; r < 4; r++){
        int ql = qb + 4*g + r;
        Ob[((size_t)n*512 + ql)*256 + h*32 + half*16 + q16] = f2bf(accA[half][r] * linvA[r]);
        Ob[((size_t)n*512 + ql + 128)*256 + h*32 + half*16 + q16] = f2bf(accB[half][r] * linvB[r]);
      }
  }
}

// ---------------- Proj GEMM 64x128 tiles, global_load_lds staging, XCD-swizzled grid ----------------
__global__ __launch_bounds__(256) void k_gemm_proj(const unsigned short* __restrict__ A,
    const unsigned short* __restrict__ Bt, const float* __restrict__ bias,
    const float* __restrict__ msa, float* __restrict__ out){
  __shared__ unsigned short As[64*64];
  __shared__ unsigned short Bs[128*64];
  int bid0 = blockIdx.x;
  int bid = (bid0 & 7) * 64 + (bid0 >> 3);   // 512 blocks: bijective XCD swizzle (512%8==0)
  int bn = bid & 1, bm = bid >> 1;
  int m0 = bm * 64, e0 = bn * 128;
  int t = threadIdx.x, lane = t & 63, w = t >> 6;
  int g = lane >> 4, mm = lane & 15;
  f32x4 acc[4][2] = {};
  for (int k0 = 0; k0 < 256; k0 += 64){
    __syncthreads();
#pragma unroll
    for (int it = 0; it < 2; it++){
      int task = t + it * 256;
      gload_lds16(A + (size_t)(m0+(task>>3))*256 + k0 + (task&7)*8, &As[task*8]);
    }
#pragma unroll
    for (int it = 0; it < 4; it++){
      int task = t + it * 256;
      gload_lds16(Bt + (size_t)(e0+(task>>3))*256 + k0 + (task&7)*8, &Bs[task*8]);
    }
    __syncthreads();
#pragma unroll
    for (int kst = 0; kst < 2; kst++){
      short8 a[4], bb[2];
#pragma unroll
      for (int i = 0; i < 4; i++)
        a[i] = *(short8*)(&As[(i*16 + mm)*64 + kst*32 + g*8]);
#pragma unroll
      for (int j = 0; j < 2; j++)
        bb[j] = *(short8*)(&Bs[(w*32 + j*16 + mm)*64 + kst*32 + g*8]);
#pragma unroll
      for (int i = 0; i < 4; i++)
#pragma unroll
        for (int j = 0; j < 2; j++)
          acc[i][j] = __builtin_amdgcn_mfma_f32_16x16x32_bf16(a[i], bb[j], acc[i][j], 0, 0, 0);
    }
  }
#pragma unroll
  for (int i = 0; i < 4; i++)
#pragma unroll
    for (int j = 0; j < 2; j++){
      int col = e0 + w*32 + j*16 + mm;
      float bc = bias[col];
#pragma unroll
      for (int r = 0; r < 4; r++){
        int gm = m0 + i*16 + 4*g + r;
        size_t idx = (size_t)gm * 256 + col;
        out[idx] = acc[i][j][r] + bc + msa[idx];
      }
    }
}

extern "C" void kernel_launch(void* const* d_in, const int* in_sizes, int n_in,
                              void* d_out, int out_size, void* d_ws, size_t ws_size,
                              hipStream_t stream){
  const float* msa    = (const float*)d_in[0];
  const float* pb     = (const float*)d_in[1];
  const float* ln_w   = (const float*)d_in[2];
  const float* ln_b   = (const float*)d_in[3];
  const float* w_qkv  = (const float*)d_in[4];
  const float* b_qkv  = (const float*)d_in[5];
  const float* w_proj = (const float*)d_in[6];
  const float* b_proj = (const float*)d_in[7];

  unsigned short* ws     = (unsigned short*)d_ws;
  unsigned short* m_bf   = ws;                      // 16384*256
  unsigned short* wqkvT  = m_bf   + 4194304;        // 768*256
  unsigned short* wprojT = wqkvT  + 196608;         // 256*256
  unsigned short* Qb     = wprojT + 65536;          // 32*8*512*32
  unsigned short* Kb     = Qb     + 4194304;
  unsigned short* Vb     = Kb     + 4194304;
  unsigned short* Ob     = Vb     + 4194304;        // 16384*256
  unsigned short* bt     = Ob     + 4194304;        // 8*512*512 (no aliasing)
  float* out = (float*)d_out;

  k_prep<<<5184, 256, 0, stream>>>(w_qkv, w_proj, pb, msa, ln_w, ln_b, wqkvT, wprojT, bt, m_bf);
  k_gemm_qkv<<<768, 256, 0, stream>>>(m_bf, wqkvT, b_qkv, Qb, Kb, Vb);
  k_attn<<<256, 512, 0, stream>>>(Qb, Kb, Vb, bt, Ob);
  k_gemm_proj<<<512, 256, 0, stream>>>(Ob, wprojT, b_proj, msa, out);
}